// Round 14
// baseline (195.383 us; speedup 1.0000x reference)
//
#include <hip/hip_runtime.h>
#include <hip/hip_bf16.h>
#include <math.h>

#define NN 16384
#define DEG 20
#define EE (NN*DEG)
#define RMAXF 3.5f
#define NGRP 5   // groups of 16 edges per block (80 edges = 4 nodes)

typedef __attribute__((ext_vector_type(8))) short short8;
typedef __attribute__((ext_vector_type(4))) float f32x4;

// soft_unit_step: exp(-1/x) for x>0 else 0  (rcp: 1-ulp, harmless vs 0.074 thr)
__device__ __forceinline__ float su_f(float x) {
    return x > 0.0f ? __expf(-__builtin_amdgcn_rcpf(x)) : 0.0f;
}
__device__ __forceinline__ ushort f2bf(float x) {
    __hip_bfloat16 h = __float2bfloat16(x);
    return *reinterpret_cast<ushort*>(&h);
}
__device__ __forceinline__ float bf2f(ushort u) {
    return __uint_as_float(((unsigned int)u) << 16);
}

// ---------------------------------------------------------------------------
// Round-25: the missing cell of the 2x2 — VALU-phase-B (R11) x 2-barrier
// schedule (R13).  Measured matrix: R11(VALU-B,3bar)=120.2, R12(MFMA-B,3bar)
// =124.3, R13(MFMA-B,2bar)=122.2 -> isolated effects: MFMA-B = +4us (bare
// latency chain, absmax 0.0156->0.031), merge = -2us.  Compose the wins:
//   interval A: C(g) MFMA-GEMM2 | A-FINISH(g+1) expf | s_b(g)      -> b3
//   interval B: A-ISSUE(g+2) loads | B(g+1) VALU-GEMM1+silu | D(g) -> b4
// B's 40-fma+silu VALU chain is independent filler for interval B (hides
// D's LDS latency + the prefetch loads), unlike MFMA-B's exposed
// ds_read->mfma->silu chain.  Drops s_embh/zero-fill/b1k/b1v; restores f32
// s_emb + wk1r/wv1r; absmax back to 0.0156.  All phase bodies verbatim-
// proven; hazard structure = R13's audited one (s_hb single-buffer: C(g)
// reads intA, B(g+1) writes intB, b3 between; s_emb[nb] written intA by
// A-FIN(g+1), read intB by B(g+1)).
// Structural notes for posterity: occupancy is pinned at 3 blocks/CU by
// s_w (33KB per 16-edge group); the fused no-s_w design failed correctness
// twice (R2/R5, non-localizable) — closed.  Schedule levers beyond this
// measured neutral (R9, R13).
// Relies on edst[e] == e/20 (contiguous segments; exploited since round 1).
// ---------------------------------------------------------------------------
__global__ __launch_bounds__(256, 3) void edge_kernel(
    const float* __restrict__ f,   const float* __restrict__ pos,
    const float* __restrict__ Wqs, const float* __restrict__ Wqv,
    const float* __restrict__ Wds, const float* __restrict__ Wdv,
    const float* __restrict__ Wk1, const float* __restrict__ Wv1,
    const float* __restrict__ Wk2, const float* __restrict__ Wv2,
    const int* __restrict__ esrc,  float* __restrict__ out)
{
    __shared__ float  s_w[2][16][260];                // 33.3 KB, D matrices (k,v)
    __shared__ __align__(16) ushort s_hb[2][16][64];  // 4 KB bf16 h (single buf)
    __shared__ __align__(16) float s_g[2][16][36];    // 4.5 KB, f[src], dbuf
    __shared__ float s_emb[2][16][10];                // 1.25 KB f32 emb, dbuf
    __shared__ float s_s1[2][16][4];                  // dbuf
    __shared__ float s_b[16][9];                      // b_i = (gv_i . s1)/sqrt3
    __shared__ __align__(4) ushort s_v[80][34];       // 5.3 KB, per-edge v (bf16)
    __shared__ float s_lg[80];                        // per-edge logits
    __shared__ float s_cut[80];                       // per-edge cutoff
    __shared__ float s_mqn[4][32];                    // mq for block's 4 nodes
    __shared__ int   s_esrc[80];                      // staged edge sources

    const int t = threadIdx.x;
    const int wave = t >> 6, lane = t & 63;
    const int qd = lane >> 4, n = lane & 15;
    const int n0 = blockIdx.x * 4;                    // first node of block
    const int E0 = n0 * DEG;                          // first edge of block

    // ---- prologue A: mq for the block's 4 dst nodes (verbatim prep math) ----
    if (t < 128) {
        int nd = t >> 5, idx = t & 31;
        const float* fr = f + (size_t)(n0 + nd) * 32;
        const float inv8 = 0.35355339059327373f; // 1/sqrt(8)
        float o_ = 0.0f;
        if (idx < 8) {
            int j = idx;
            #pragma unroll
            for (int i = 0; i < 8; i++) {
                float qs = 0.0f;
                #pragma unroll
                for (int a = 0; a < 8; a++) qs = fmaf(fr[a], Wqs[a * 8 + i], qs);
                o_ = fmaf(qs * inv8, Wds[i * 8 + j], o_);
            }
        } else {
            int kk = idx - 8;
            int j = kk / 3, c = kk - 3 * j;
            #pragma unroll
            for (int i = 0; i < 8; i++) {
                float qv = 0.0f;
                #pragma unroll
                for (int a = 0; a < 8; a++) qv = fmaf(fr[8 + 3 * a + c], Wqv[a * 8 + i], qv);
                o_ = fmaf(qv * inv8, Wdv[i * 8 + j], o_);
            }
            o_ *= 0.5773502691896258f; // 1/sqrt(3)
        }
        s_mqn[nd][idx] = o_;
    }
    if (t < 80) s_esrc[t] = esrc[E0 + t];
    __syncthreads(); // b0: s_esrc / s_mqn visible

    // ---- prologue B: W1 rows for this lane (20 regs, R11 form) ----
    float wk1r[10], wv1r[10];
    #pragma unroll
    for (int j = 0; j < 10; j++) {
        wk1r[j] = Wk1[j * 64 + lane];
        wv1r[j] = Wv1[j * 64 + lane];
    }

    // ---- prologue C: GEMM2 B-fragments packed directly from W2 (both nets) ----
    short8 breg[2][2][4];
    #pragma unroll
    for (int net = 0; net < 2; net++) {
        const float* W2 = net ? Wv2 : Wk2;
        #pragma unroll
        for (int s = 0; s < 2; s++)
            #pragma unroll
            for (int jj = 0; jj < 4; jj++) {
                int col = (wave * 4 + jj) * 16 + n;
                union { ushort u[8]; short8 v; } bf;
                #pragma unroll
                for (int j = 0; j < 8; j++) {
                    int k0 = s * 32 + qd * 8 + j;
                    bf.u[j] = f2bf(W2[k0 * 256 + col] * 0.125f);
                }
                breg[net][s][jj] = bf.v;
            }
    }

    // ---- initial phase A(0)+A2(0) into buffer 0 ----
    {
        int e = t >> 4, rl = t & 15;
        if (rl < 11) {
            int s = s_esrc[e];
            int d = n0;                    // edge 0..15 -> node n0 (e/20==0)
            float vx = pos[s * 3 + 0] - pos[d * 3 + 0];
            float vy = pos[s * 3 + 1] - pos[d * 3 + 1];
            float vz = pos[s * 3 + 2] - pos[d * 3 + 2];
            float r = sqrtf(vx * vx + vy * vy + vz * vz);
            if (rl < 10) {
                const float step = RMAXF / 11.0f;
                const float invstep = 11.0f / RMAXF;
                const float K = 26.66929988626f; // 1.14136*e^2*sqrt(10)
                float dd = (r - step * (float)(rl + 1)) * invstep;
                s_emb[0][e][rl] = K * su_f(dd + 1.0f) * su_f(1.0f - dd);
            } else {
                float invr = __builtin_amdgcn_rcpf(r);
                const float sqrt3 = 1.7320508075688772f;
                s_s1[0][e][0] = sqrt3 * vx * invr;
                s_s1[0][e][1] = sqrt3 * vy * invr;
                s_s1[0][e][2] = sqrt3 * vz * invr;
                s_cut[e] = su_f(10.0f * (1.0f - r / RMAXF));
            }
        }
        if (t < 128) {
            int el = t >> 3, c4 = t & 7;
            int s = s_esrc[el];
            float4 x = *reinterpret_cast<const float4*>(f + (size_t)s * 32 + c4 * 4);
            *reinterpret_cast<float4*>(&s_g[0][el][c4 * 4]) = x;
        }
    }
    __syncthreads(); // b1: buffer-0 A-data visible

    // ---- pre-loop: A-ISSUE(1) + B(0) (VALU) ----
    float psx = 0.f, psy = 0.f, psz = 0.f, pdx = 0.f, pdy = 0.f, pdz = 0.f;
    float4 pf4 = {0.f, 0.f, 0.f, 0.f};
    {
        int e = t >> 4, rl = t & 15;
        if (rl < 11) {
            int s = s_esrc[16 + e];
            int d = n0 + (16 + e) / DEG;
            psx = pos[s * 3 + 0]; psy = pos[s * 3 + 1]; psz = pos[s * 3 + 2];
            pdx = pos[d * 3 + 0]; pdy = pos[d * 3 + 1]; pdz = pos[d * 3 + 2];
        }
        if (t < 128) {
            int el = t >> 3, c4 = t & 7;
            int s = s_esrc[16 + el];
            pf4 = *reinterpret_cast<const float4*>(f + (size_t)s * 32 + c4 * 4);
        }
    }
    {   // B(0): GEMM1 via VALU (W1 in regs) + silu -> s_hb
        const float invsq10 = 0.31622776601683794f; // 1/sqrt(10)
        #pragma unroll
        for (int e = 0; e < 4; e++) {
            int el = wave * 4 + e;
            float ak = 0.0f, av = 0.0f;
            #pragma unroll
            for (int j = 0; j < 10; j++) {
                float ej = s_emb[0][el][j];
                ak = fmaf(ej, wk1r[j], ak);
                av = fmaf(ej, wv1r[j], av);
            }
            ak *= invsq10; av *= invsq10;
            float hk = ak * __builtin_amdgcn_rcpf(1.0f + __expf(-ak));
            float hv = av * __builtin_amdgcn_rcpf(1.0f + __expf(-av));
            int pos_ = ((((lane >> 3) ^ (el & 7))) << 3) | (lane & 7);
            s_hb[0][el][pos_] = f2bf(hk);
            s_hb[1][el][pos_] = f2bf(hv);
        }
    }
    __syncthreads(); // b2: s_hb(0) visible for C(0)

    for (int g = 0; g < NGRP; g++) {
        const int cb = g & 1, nb = cb ^ 1;
        const int le0 = g * 16;            // local edge base
        const bool more = (g + 1 < NGRP);

        // ================= interval A: C(g) | A-FINISH(g+1) | s_b(g) ========
        #pragma unroll
        for (int net = 0; net < 2; net++) {
            short8 ha0 = *(const short8*)&s_hb[net][n][((qd ^ (n & 7)) << 3)];
            short8 ha1 = *(const short8*)&s_hb[net][n][(((4 + qd) ^ (n & 7)) << 3)];
            #pragma unroll
            for (int jj = 0; jj < 4; jj++) {
                int tt = wave * 4 + jj;
                f32x4 d = {0.0f, 0.0f, 0.0f, 0.0f};
                d = __builtin_amdgcn_mfma_f32_16x16x32_bf16(ha0, breg[net][0][jj], d, 0, 0, 0);
                d = __builtin_amdgcn_mfma_f32_16x16x32_bf16(ha1, breg[net][1][jj], d, 0, 0, 0);
                #pragma unroll
                for (int r = 0; r < 4; r++)
                    s_w[net][4 * qd + r][tt * 16 + n] = d[r]; // D: row=4*quad+reg, col=n
            }
        }
        if (more) { // A-FINISH(g+1): VALU on A-ISSUE regs -> buffers nb
            int e = t >> 4, rl = t & 15;
            if (rl < 11) {
                float vx = psx - pdx, vy = psy - pdy, vz = psz - pdz;
                float r = sqrtf(vx * vx + vy * vy + vz * vz);
                if (rl < 10) {
                    const float step = RMAXF / 11.0f;
                    const float invstep = 11.0f / RMAXF;
                    const float K = 26.66929988626f; // 1.14136*e^2*sqrt(10)
                    float dd = (r - step * (float)(rl + 1)) * invstep;
                    s_emb[nb][e][rl] = K * su_f(dd + 1.0f) * su_f(1.0f - dd);
                } else {
                    float invr = __builtin_amdgcn_rcpf(r);
                    const float sqrt3 = 1.7320508075688772f;
                    s_s1[nb][e][0] = sqrt3 * vx * invr;
                    s_s1[nb][e][1] = sqrt3 * vy * invr;
                    s_s1[nb][e][2] = sqrt3 * vz * invr;
                    s_cut[le0 + 16 + e] = su_f(10.0f * (1.0f - r / RMAXF));
                }
            }
            if (t < 128) {
                int el = t >> 3, c4 = t & 7;
                *reinterpret_cast<float4*>(&s_g[nb][el][c4 * 4]) = pf4;
            }
        }
        if (t < 128) { // s_b(g)
            int el = t >> 3, k = t & 7;
            const float inv_sqrt3 = 0.5773502691896258f;
            s_b[el][k] = (s_g[cb][el][8 + 3 * k + 0] * s_s1[cb][el][0] +
                          s_g[cb][el][8 + 3 * k + 1] * s_s1[cb][el][1] +
                          s_g[cb][el][8 + 3 * k + 2] * s_s1[cb][el][2]) * inv_sqrt3;
        }
        __syncthreads(); // b3: s_w / s_emb[nb] / s_g[nb] / s_b ready

        // ====== interval B: A-ISSUE(g+2) | B(g+1) VALU | D(g) ==============
        if (g + 2 < NGRP) { // A-ISSUE(g+2): global loads in flight under B+D
            int e = t >> 4, rl = t & 15;
            if (rl < 11) {
                int s = s_esrc[le0 + 32 + e];
                int d = n0 + (le0 + 32 + e) / DEG;  // edst[e] == e/20
                psx = pos[s * 3 + 0]; psy = pos[s * 3 + 1]; psz = pos[s * 3 + 2];
                pdx = pos[d * 3 + 0]; pdy = pos[d * 3 + 1]; pdz = pos[d * 3 + 2];
            }
            if (t < 128) {
                int el = t >> 3, c4 = t & 7;
                int s = s_esrc[le0 + 32 + el];
                pf4 = *reinterpret_cast<const float4*>(f + (size_t)s * 32 + c4 * 4);
            }
        }
        if (more) { // B(g+1): GEMM1 via VALU (reads s_emb[nb]) + silu -> s_hb
            const float invsq10 = 0.31622776601683794f; // 1/sqrt(10)
            #pragma unroll
            for (int e = 0; e < 4; e++) {
                int el = wave * 4 + e;
                float ak = 0.0f, av = 0.0f;
                #pragma unroll
                for (int j = 0; j < 10; j++) {
                    float ej = s_emb[nb][el][j];
                    ak = fmaf(ej, wk1r[j], ak);
                    av = fmaf(ej, wv1r[j], av);
                }
                ak *= invsq10; av *= invsq10;
                float hk = ak * __builtin_amdgcn_rcpf(1.0f + __expf(-ak));
                float hv = av * __builtin_amdgcn_rcpf(1.0f + __expf(-av));
                int pos_ = ((((lane >> 3) ^ (el & 7))) << 3) | (lane & 7);
                s_hb[0][el][pos_] = f2bf(hk);
                s_hb[1][el][pos_] = f2bf(hv);
            }
        }
        { // D(g): net-split TP (verbatim R11/R13)
            int u = t & 127;
            int el = u >> 3, o = u & 7;
            int le = le0 + el;
            float g_[32];
            #pragma unroll
            for (int v4 = 0; v4 < 8; v4++) {
                float4 x = *reinterpret_cast<const float4*>(&s_g[cb][el][v4 * 4]);
                g_[v4 * 4 + 0] = x.x; g_[v4 * 4 + 1] = x.y;
                g_[v4 * 4 + 2] = x.z; g_[v4 * 4 + 3] = x.w;
            }
            const float nrm = 0.25f; // 1/(sqrt(8)*sqrt(2))

            if (t < 128) {           // --- complete k-net for (el,o) -> logit ---
                int nd = le / DEG;   // local dst node of this edge
                const float* wk = s_w[0][el];
                float ks = 0.0f, uk = 0.0f;
                #pragma unroll
                for (int i = 0; i < 8; i++) {
                    ks += g_[i] * wk[i * 8 + o] + s_b[el][i] * wk[64 + i * 8 + o];
                    uk = fmaf(g_[i], wk[128 + i * 8 + o], uk);
                }
                float contrib = s_mqn[nd][o] * (ks * nrm);
                #pragma unroll
                for (int c = 0; c < 3; c++) {
                    float tk = 0.0f;
                    #pragma unroll
                    for (int i = 0; i < 8; i++)
                        tk = fmaf(g_[8 + 3 * i + c], wk[192 + i * 8 + o], tk);
                    float kv_c = nrm * (s_s1[cb][el][c] * uk + tk);
                    contrib = fmaf(s_mqn[nd][8 + 3 * o + c], kv_c, contrib);
                }
                contrib += __shfl_xor(contrib, 1);
                contrib += __shfl_xor(contrib, 2);
                contrib += __shfl_xor(contrib, 4);
                if (o == 0) s_lg[le] = contrib * 0.08838834764831845f; // 1/(8*sqrt2)
            } else {                 // --- complete v-net for (el,o) -> s_v ---
                const float* wv = s_w[1][el];
                float vs = 0.0f, uv = 0.0f;
                #pragma unroll
                for (int i = 0; i < 8; i++) {
                    vs += g_[i] * wv[i * 8 + o] + s_b[el][i] * wv[64 + i * 8 + o];
                    uv = fmaf(g_[i], wv[128 + i * 8 + o], uv);
                }
                s_v[le][o] = f2bf(vs * nrm);
                #pragma unroll
                for (int c = 0; c < 3; c++) {
                    float tv = 0.0f;
                    #pragma unroll
                    for (int i = 0; i < 8; i++)
                        tv = fmaf(g_[8 + 3 * i + c], wv[192 + i * 8 + o], tv);
                    s_v[le][8 + 3 * o + c] = f2bf(nrm * (s_s1[cb][el][c] * uv + tv));
                }
            }
        }
        __syncthreads(); // b4: s_v/s_lg done; s_hb(g+1) ready for C(g+1)
    }

    // ---- epilogue: per-node softmax + weighted sum (proven out_kernel math).
    //      wave w handles node n0+w; both 32-lane halves compute identically.
    {
        int base_le = DEG * wave;
        int h32 = lane & 32;
        int hl = lane & 31;
        float lg = -INFINITY, cw = 0.0f;
        if (hl < DEG) {
            lg = s_lg[base_le + hl];
            cw = s_cut[base_le + hl];
        }
        float mx = lg;
        mx = fmaxf(mx, __shfl_xor(mx, 16));
        mx = fmaxf(mx, __shfl_xor(mx, 8));
        mx = fmaxf(mx, __shfl_xor(mx, 4));
        mx = fmaxf(mx, __shfl_xor(mx, 2));
        mx = fmaxf(mx, __shfl_xor(mx, 1));

        float ew = cw * __expf(lg - mx);
        float z = ew;
        z += __shfl_xor(z, 16);
        z += __shfl_xor(z, 8);
        z += __shfl_xor(z, 4);
        z += __shfl_xor(z, 2);
        z += __shfl_xor(z, 1);
        z = (z == 0.0f) ? 1.0f : z;
        float coef = sqrtf(ew * __builtin_amdgcn_rcpf(z) + 1e-12f);

        float acc = 0.0f;
        #pragma unroll
        for (int ee = 0; ee < DEG; ee++) {
            float ce = __shfl(coef, h32 + ee);
            acc = fmaf(ce, bf2f(s_v[base_le + ee][hl]), acc);
        }
        if (lane < 32) out[(size_t)(n0 + wave) * 32 + hl] = acc;
    }
}

// ---------------------------------------------------------------------------
extern "C" void kernel_launch(void* const* d_in, const int* in_sizes, int n_in,
                              void* d_out, int out_size, void* d_ws, size_t ws_size,
                              hipStream_t stream) {
    const float* f    = (const float*)d_in[0];
    const float* pos  = (const float*)d_in[1];
    const float* Wqs  = (const float*)d_in[2];
    const float* Wqv  = (const float*)d_in[3];
    const float* Wk1  = (const float*)d_in[4];
    const float* Wk2  = (const float*)d_in[5];
    const float* Wv1  = (const float*)d_in[6];
    const float* Wv2  = (const float*)d_in[7];
    const float* Wds  = (const float*)d_in[8];
    const float* Wdv  = (const float*)d_in[9];
    const int* esrc   = (const int*)d_in[10];
    float* out        = (float*)d_out;

    edge_kernel<<<dim3(NN / 4), dim3(256), 0, stream>>>(
        f, pos, Wqs, Wqv, Wds, Wdv, Wk1, Wv1, Wk2, Wv2, esrc, out);
}

// Round 15
// 177.751 us; speedup vs baseline: 1.0992x; 1.0992x over previous
//
#include <hip/hip_runtime.h>
#include <hip/hip_bf16.h>
#include <math.h>

#define NN 16384
#define DEG 20
#define EE (NN*DEG)
#define RMAXF 3.5f
#define NGRP 5   // groups of 16 edges per block (80 edges = 4 nodes)

typedef __attribute__((ext_vector_type(8))) short short8;
typedef __attribute__((ext_vector_type(4))) float f32x4;

// soft_unit_step: exp(-1/x) for x>0 else 0  (rcp: 1-ulp, harmless vs 0.074 thr)
__device__ __forceinline__ float su_f(float x) {
    return x > 0.0f ? __expf(-__builtin_amdgcn_rcpf(x)) : 0.0f;
}
__device__ __forceinline__ ushort f2bf(float x) {
    __hip_bfloat16 h = __float2bfloat16(x);
    return *reinterpret_cast<ushort*>(&h);
}
__device__ __forceinline__ float bf2f(ushort u) {
    return __uint_as_float(((unsigned int)u) << 16);
}

// ---------------------------------------------------------------------------
// Round-26 == R11 restored verbatim (the measured optimum: 120.2us/dispatch,
// bench 177.9us, absmax 0.015625).
//
// Completed 2x2 design matrix (dispatch us):
//             3-barrier   2-barrier
//   VALU-B     120.2(R11)  147(R14, spilled: WRITE 2->19MB)
//   MFMA-B     124.3(R12)  122.2(R13)
// Composition fails via register pressure, not schedule.  Lever ledger:
//  banked:   phase-A parallelize + stride fix (R3, -26us), net/wave splits
//            (R10/R11, -29us), slot cuts (R7, -12us)
//  neutral:  load pipelining (R9), barrier merge with VALU-B's regs (R13/14)
//  negative: MFMA-GEMM1 (R12, latency-exposed), bf16 s_w (R6: LDS shrink
//            does NOT raise occupancy — HW-capped ~12 waves/CU), branchless
//            D (R4, scratch), (256,4) bounds (R1, 1KB/thread spill)
//  closed:   fused no-s_w consumption (R2/R5: non-localizable correctness
//            failures), i/o-swap repack (R5)
// Residual profile: VALUBusy 55%, MfmaUtil 7.4%, HBM 1.2%, conflicts 5.7e6
// (~7% of cycles) — fine-grained lockstep latency; no remaining single
// lever outside the failed classes.
// Relies on edst[e] == e/20 (contiguous segments; exploited since round 1).
// ---------------------------------------------------------------------------
__global__ __launch_bounds__(256, 3) void edge_kernel(
    const float* __restrict__ f,   const float* __restrict__ pos,
    const float* __restrict__ Wqs, const float* __restrict__ Wqv,
    const float* __restrict__ Wds, const float* __restrict__ Wdv,
    const float* __restrict__ Wk1, const float* __restrict__ Wv1,
    const float* __restrict__ Wk2, const float* __restrict__ Wv2,
    const int* __restrict__ esrc,  float* __restrict__ out)
{
    __shared__ float  s_w[2][16][260];                // 33.3 KB, D matrices (k,v)
    __shared__ __align__(16) ushort s_hb[2][16][64];  // 4 KB bf16 h, XOR-swizzled
    __shared__ __align__(16) float s_g[2][16][36];    // 4.5 KB, f[src], dbuf
    __shared__ float s_emb[2][16][10];                // dbuf
    __shared__ float s_s1[2][16][4];                  // dbuf
    __shared__ float s_b[16][9];                      // b_i = (gv_i . s1)/sqrt3
    __shared__ __align__(4) ushort s_v[80][34];       // 5.3 KB, per-edge v (bf16)
    __shared__ float s_lg[80];                        // per-edge logits
    __shared__ float s_cut[80];                       // per-edge cutoff
    __shared__ float s_mqn[4][32];                    // mq for block's 4 nodes
    __shared__ int   s_esrc[80];                      // staged edge sources

    const int t = threadIdx.x;
    const int wave = t >> 6, lane = t & 63;
    const int qd = lane >> 4, n = lane & 15;
    const int n0 = blockIdx.x * 4;                    // first node of block
    const int E0 = n0 * DEG;                          // first edge of block

    // ---- prologue A: mq for the block's 4 dst nodes (verbatim prep math) ----
    if (t < 128) {
        int nd = t >> 5, idx = t & 31;
        const float* fr = f + (size_t)(n0 + nd) * 32;
        const float inv8 = 0.35355339059327373f; // 1/sqrt(8)
        float o_ = 0.0f;
        if (idx < 8) {
            int j = idx;
            #pragma unroll
            for (int i = 0; i < 8; i++) {
                float qs = 0.0f;
                #pragma unroll
                for (int a = 0; a < 8; a++) qs = fmaf(fr[a], Wqs[a * 8 + i], qs);
                o_ = fmaf(qs * inv8, Wds[i * 8 + j], o_);
            }
        } else {
            int kk = idx - 8;
            int j = kk / 3, c = kk - 3 * j;
            #pragma unroll
            for (int i = 0; i < 8; i++) {
                float qv = 0.0f;
                #pragma unroll
                for (int a = 0; a < 8; a++) qv = fmaf(fr[8 + 3 * a + c], Wqv[a * 8 + i], qv);
                o_ = fmaf(qv * inv8, Wdv[i * 8 + j], o_);
            }
            o_ *= 0.5773502691896258f; // 1/sqrt(3)
        }
        s_mqn[nd][idx] = o_;
    }
    if (t < 80) s_esrc[t] = esrc[E0 + t];
    __syncthreads(); // b0: s_esrc / s_mqn visible

    // ---- prologue B: W1 rows for this lane (20 regs) ----
    float wk1r[10], wv1r[10];
    #pragma unroll
    for (int j = 0; j < 10; j++) {
        wk1r[j] = Wk1[j * 64 + lane];
        wv1r[j] = Wv1[j * 64 + lane];
    }

    // ---- prologue C: B fragments packed directly from W2 (both nets) ----
    short8 breg[2][2][4];
    #pragma unroll
    for (int net = 0; net < 2; net++) {
        const float* W2 = net ? Wv2 : Wk2;
        #pragma unroll
        for (int s = 0; s < 2; s++)
            #pragma unroll
            for (int jj = 0; jj < 4; jj++) {
                int col = (wave * 4 + jj) * 16 + n;
                union { ushort u[8]; short8 v; } bf;
                #pragma unroll
                for (int j = 0; j < 8; j++) {
                    int k0 = s * 32 + qd * 8 + j;
                    bf.u[j] = f2bf(W2[k0 * 256 + col] * 0.125f);
                }
                breg[net][s][jj] = bf.v;
            }
    }

    // ---- initial phase A(0)+A2(0) into buffer 0 ----
    {
        int e = t >> 4, rl = t & 15;
        if (rl < 11) {
            int s = s_esrc[e];
            int d = n0;                    // edge 0..15 -> node n0 (e/20==0)
            float vx = pos[s * 3 + 0] - pos[d * 3 + 0];
            float vy = pos[s * 3 + 1] - pos[d * 3 + 1];
            float vz = pos[s * 3 + 2] - pos[d * 3 + 2];
            float r = sqrtf(vx * vx + vy * vy + vz * vz);
            if (rl < 10) {
                const float step = RMAXF / 11.0f;
                const float invstep = 11.0f / RMAXF;
                const float K = 26.66929988626f; // 1.14136*e^2*sqrt(10)
                float dd = (r - step * (float)(rl + 1)) * invstep;
                s_emb[0][e][rl] = K * su_f(dd + 1.0f) * su_f(1.0f - dd);
            } else {
                float invr = __builtin_amdgcn_rcpf(r);
                const float sqrt3 = 1.7320508075688772f;
                s_s1[0][e][0] = sqrt3 * vx * invr;
                s_s1[0][e][1] = sqrt3 * vy * invr;
                s_s1[0][e][2] = sqrt3 * vz * invr;
                s_cut[e] = su_f(10.0f * (1.0f - r / RMAXF));
            }
        }
        if (t < 128) {
            int el = t >> 3, c4 = t & 7;
            int s = s_esrc[el];
            float4 x = *reinterpret_cast<const float4*>(f + (size_t)s * 32 + c4 * 4);
            *reinterpret_cast<float4*>(&s_g[0][el][c4 * 4]) = x;
        }
    }
    __syncthreads(); // b1 (once)

    for (int g = 0; g < NGRP; g++) {
        const int cb = g & 1, nbuf = cb ^ 1;
        const int le0 = g * 16;            // local edge base
        const bool more = (g + 1 < NGRP);

        // ---- A-ISSUE(g+1): pure global loads into registers ----
        float psx = 0.f, psy = 0.f, psz = 0.f, pdx = 0.f, pdy = 0.f, pdz = 0.f;
        float4 pf4 = {0.f, 0.f, 0.f, 0.f};
        {
            int e = t >> 4, rl = t & 15;
            if (more && rl < 11) {
                int s = s_esrc[le0 + 16 + e];
                int d = n0 + (le0 + 16 + e) / DEG;  // edst[e] == e/20
                psx = pos[s * 3 + 0]; psy = pos[s * 3 + 1]; psz = pos[s * 3 + 2];
                pdx = pos[d * 3 + 0]; pdy = pos[d * 3 + 1]; pdz = pos[d * 3 + 2];
            }
            if (more && t < 128) {
                int el = t >> 3, c4 = t & 7;
                int s = s_esrc[le0 + 16 + el];
                pf4 = *reinterpret_cast<const float4*>(f + (size_t)s * 32 + c4 * 4);
            }
        }

        // ---- phase B(g): GEMM1 (W1 in regs) + silu -> s_hb; s_b ----
        {
            const float invsq10 = 0.31622776601683794f; // 1/sqrt(10)
            #pragma unroll
            for (int e = 0; e < 4; e++) {
                int el = wave * 4 + e;
                float ak = 0.0f, av = 0.0f;
                #pragma unroll
                for (int j = 0; j < 10; j++) {
                    float ej = s_emb[cb][el][j];
                    ak = fmaf(ej, wk1r[j], ak);
                    av = fmaf(ej, wv1r[j], av);
                }
                ak *= invsq10; av *= invsq10;
                float hk = ak * __builtin_amdgcn_rcpf(1.0f + __expf(-ak));
                float hv = av * __builtin_amdgcn_rcpf(1.0f + __expf(-av));
                int pos_ = ((((lane >> 3) ^ (el & 7))) << 3) | (lane & 7);
                s_hb[0][el][pos_] = f2bf(hk);
                s_hb[1][el][pos_] = f2bf(hv);
            }
            if (t < 128) {
                int el = t >> 3, k = t & 7;
                const float inv_sqrt3 = 0.5773502691896258f;
                s_b[el][k] = (s_g[cb][el][8 + 3 * k + 0] * s_s1[cb][el][0] +
                              s_g[cb][el][8 + 3 * k + 1] * s_s1[cb][el][1] +
                              s_g[cb][el][8 + 3 * k + 2] * s_s1[cb][el][2]) * inv_sqrt3;
            }
        }

        // ---- A-FINISH(g+1): VALU on loaded regs -> buffer nbuf ----
        if (more) {
            int e = t >> 4, rl = t & 15;
            if (rl < 11) {
                float vx = psx - pdx, vy = psy - pdy, vz = psz - pdz;
                float r = sqrtf(vx * vx + vy * vy + vz * vz);
                if (rl < 10) {
                    const float step = RMAXF / 11.0f;
                    const float invstep = 11.0f / RMAXF;
                    const float K = 26.66929988626f; // 1.14136*e^2*sqrt(10)
                    float dd = (r - step * (float)(rl + 1)) * invstep;
                    s_emb[nbuf][e][rl] = K * su_f(dd + 1.0f) * su_f(1.0f - dd);
                } else {
                    float invr = __builtin_amdgcn_rcpf(r);
                    const float sqrt3 = 1.7320508075688772f;
                    s_s1[nbuf][e][0] = sqrt3 * vx * invr;
                    s_s1[nbuf][e][1] = sqrt3 * vy * invr;
                    s_s1[nbuf][e][2] = sqrt3 * vz * invr;
                    s_cut[le0 + 16 + e] = su_f(10.0f * (1.0f - r / RMAXF));
                }
            }
            if (t < 128) {
                int el = t >> 3, c4 = t & 7;
                *reinterpret_cast<float4*>(&s_g[nbuf][el][c4 * 4]) = pf4;
            }
        }
        __syncthreads(); // b2

        // ---- phase C: MFMA GEMM2 for both nets -> s_w[net] ----
        #pragma unroll
        for (int net = 0; net < 2; net++) {
            short8 ha0 = *(const short8*)&s_hb[net][n][((qd ^ (n & 7)) << 3)];
            short8 ha1 = *(const short8*)&s_hb[net][n][(((4 + qd) ^ (n & 7)) << 3)];
            #pragma unroll
            for (int jj = 0; jj < 4; jj++) {
                int tt = wave * 4 + jj;
                f32x4 d = {0.0f, 0.0f, 0.0f, 0.0f};
                d = __builtin_amdgcn_mfma_f32_16x16x32_bf16(ha0, breg[net][0][jj], d, 0, 0, 0);
                d = __builtin_amdgcn_mfma_f32_16x16x32_bf16(ha1, breg[net][1][jj], d, 0, 0, 0);
                #pragma unroll
                for (int r = 0; r < 4; r++)
                    s_w[net][4 * qd + r][tt * 16 + n] = d[r]; // D: row=4*quad+reg, col=n
            }
        }
        __syncthreads(); // b3

        // ---- phase D: net-split TP. waves 0-1: k-net -> logit; 2-3: v-net ----
        {
            int u = t & 127;
            int el = u >> 3, o = u & 7;
            int le = le0 + el;
            float g_[32];
            #pragma unroll
            for (int v4 = 0; v4 < 8; v4++) {
                float4 x = *reinterpret_cast<const float4*>(&s_g[cb][el][v4 * 4]);
                g_[v4 * 4 + 0] = x.x; g_[v4 * 4 + 1] = x.y;
                g_[v4 * 4 + 2] = x.z; g_[v4 * 4 + 3] = x.w;
            }
            const float nrm = 0.25f; // 1/(sqrt(8)*sqrt(2))

            if (t < 128) {           // --- complete k-net for (el,o) -> logit ---
                int nd = le / DEG;   // local dst node of this edge
                const float* wk = s_w[0][el];
                float ks = 0.0f, uk = 0.0f;
                #pragma unroll
                for (int i = 0; i < 8; i++) {
                    ks += g_[i] * wk[i * 8 + o] + s_b[el][i] * wk[64 + i * 8 + o];
                    uk = fmaf(g_[i], wk[128 + i * 8 + o], uk);
                }
                float contrib = s_mqn[nd][o] * (ks * nrm);
                #pragma unroll
                for (int c = 0; c < 3; c++) {
                    float tk = 0.0f;
                    #pragma unroll
                    for (int i = 0; i < 8; i++)
                        tk = fmaf(g_[8 + 3 * i + c], wk[192 + i * 8 + o], tk);
                    float kv_c = nrm * (s_s1[cb][el][c] * uk + tk);
                    contrib = fmaf(s_mqn[nd][8 + 3 * o + c], kv_c, contrib);
                }
                contrib += __shfl_xor(contrib, 1);
                contrib += __shfl_xor(contrib, 2);
                contrib += __shfl_xor(contrib, 4);
                if (o == 0) s_lg[le] = contrib * 0.08838834764831845f; // 1/(8*sqrt2)
            } else {                 // --- complete v-net for (el,o) -> s_v ---
                const float* wv = s_w[1][el];
                float vs = 0.0f, uv = 0.0f;
                #pragma unroll
                for (int i = 0; i < 8; i++) {
                    vs += g_[i] * wv[i * 8 + o] + s_b[el][i] * wv[64 + i * 8 + o];
                    uv = fmaf(g_[i], wv[128 + i * 8 + o], uv);
                }
                s_v[le][o] = f2bf(vs * nrm);
                #pragma unroll
                for (int c = 0; c < 3; c++) {
                    float tv = 0.0f;
                    #pragma unroll
                    for (int i = 0; i < 8; i++)
                        tv = fmaf(g_[8 + 3 * i + c], wv[192 + i * 8 + o], tv);
                    s_v[le][8 + 3 * o + c] = f2bf(nrm * (s_s1[cb][el][c] * uv + tv));
                }
            }
        }
        __syncthreads(); // b4: protects s_hb/s_w/s_b for next group, s_v/s_lg for epilogue
    }

    // ---- epilogue: per-node softmax + weighted sum (proven out_kernel math).
    //      wave w handles node n0+w; both 32-lane halves compute identically.
    {
        int base_le = DEG * wave;
        int h32 = lane & 32;
        int hl = lane & 31;
        float lg = -INFINITY, cw = 0.0f;
        if (hl < DEG) {
            lg = s_lg[base_le + hl];
            cw = s_cut[base_le + hl];
        }
        float mx = lg;
        mx = fmaxf(mx, __shfl_xor(mx, 16));
        mx = fmaxf(mx, __shfl_xor(mx, 8));
        mx = fmaxf(mx, __shfl_xor(mx, 4));
        mx = fmaxf(mx, __shfl_xor(mx, 2));
        mx = fmaxf(mx, __shfl_xor(mx, 1));

        float ew = cw * __expf(lg - mx);
        float z = ew;
        z += __shfl_xor(z, 16);
        z += __shfl_xor(z, 8);
        z += __shfl_xor(z, 4);
        z += __shfl_xor(z, 2);
        z += __shfl_xor(z, 1);
        z = (z == 0.0f) ? 1.0f : z;
        float coef = sqrtf(ew * __builtin_amdgcn_rcpf(z) + 1e-12f);

        float acc = 0.0f;
        #pragma unroll
        for (int ee = 0; ee < DEG; ee++) {
            float ce = __shfl(coef, h32 + ee);
            acc = fmaf(ce, bf2f(s_v[base_le + ee][hl]), acc);
        }
        if (lane < 32) out[(size_t)(n0 + wave) * 32 + hl] = acc;
    }
}

// ---------------------------------------------------------------------------
extern "C" void kernel_launch(void* const* d_in, const int* in_sizes, int n_in,
                              void* d_out, int out_size, void* d_ws, size_t ws_size,
                              hipStream_t stream) {
    const float* f    = (const float*)d_in[0];
    const float* pos  = (const float*)d_in[1];
    const float* Wqs  = (const float*)d_in[2];
    const float* Wqv  = (const float*)d_in[3];
    const float* Wk1  = (const float*)d_in[4];
    const float* Wk2  = (const float*)d_in[5];
    const float* Wv1  = (const float*)d_in[6];
    const float* Wv2  = (const float*)d_in[7];
    const float* Wds  = (const float*)d_in[8];
    const float* Wdv  = (const float*)d_in[9];
    const int* esrc   = (const int*)d_in[10];
    float* out        = (float*)d_out;

    edge_kernel<<<dim3(NN / 4), dim3(256), 0, stream>>>(
        f, pos, Wqs, Wqv, Wds, Wdv, Wk1, Wv1, Wk2, Wv2, esrc, out);
}